// Round 14
// baseline (220.102 us; speedup 1.0000x reference)
//
#include <hip/hip_runtime.h>
#include <cstdint>

#define NN   4096
#define EMB  16
#define CIN  64
#define COUT 64
#define BB   16

typedef __attribute__((ext_vector_type(8))) short short8v;
typedef __attribute__((ext_vector_type(4))) float f32x4;

__device__ inline ushort f2bf(float f) {
    uint32_t u = __builtin_bit_cast(uint32_t, f);
    uint32_t r = (u + 0x7FFFu + ((u >> 16) & 1u)) >> 16;
    return (ushort)r;
}
__device__ inline float bf2f(ushort u) {
    uint32_t v = ((uint32_t)u) << 16;
    return __builtin_bit_cast(float, v);
}
// async global->LDS, 16B per lane. LDS dest = wave-uniform base + lane*16.
__device__ inline void gload_lds16(const ushort* g, ushort* l) {
    __builtin_amdgcn_global_load_lds(
        (const __attribute__((address_space(1))) void*)g,
        (__attribute__((address_space(3))) void*)l, 16, 0, 0);
}

// ---------------------------------------------------------------------------
// Kernel 1: A = exp(relu(E @ E^T)) UNNORMALIZED bf16 + invsum[n] = 1/rowsum.
// (r13-proven; normalization folded into combine)
// ---------------------------------------------------------------------------
__global__ __launch_bounds__(256) void adj_softmax_kernel(
    const float* __restrict__ E, ushort* __restrict__ A,
    float* __restrict__ invsum)
{
    __shared__ float cl[128][20];

    const int r0 = blockIdx.x * 16;
    const int t  = threadIdx.x;
    const int i  = t >> 5;        // 0..7
    const int j  = t & 31;        // 0..31

    float er[2][16];
    #pragma unroll
    for (int rr = 0; rr < 2; ++rr) {
        const float4* ep = reinterpret_cast<const float4*>(
            E + (size_t)(r0 + i + rr * 8) * EMB);
        float4 a = ep[0], b = ep[1], c = ep[2], d = ep[3];
        er[rr][0]=a.x; er[rr][1]=a.y; er[rr][2]=a.z; er[rr][3]=a.w;
        er[rr][4]=b.x; er[rr][5]=b.y; er[rr][6]=b.z; er[rr][7]=b.w;
        er[rr][8]=c.x; er[rr][9]=c.y; er[rr][10]=c.z; er[rr][11]=c.w;
        er[rr][12]=d.x; er[rr][13]=d.y; er[rr][14]=d.z; er[rr][15]=d.w;
    }

    const int scol = t >> 1;
    const int skh  = (t & 1) * 8;

    float rsum[2] = {0.0f, 0.0f};

    float4 v0, v1;
    {
        const float4* src = reinterpret_cast<const float4*>(
            E + (size_t)scol * EMB + skh);
        v0 = src[0]; v1 = src[1];
    }
    for (int g = 0; g < 32; ++g) {
        __syncthreads();
        *reinterpret_cast<float4*>(&cl[scol][skh])     = v0;
        *reinterpret_cast<float4*>(&cl[scol][skh + 4]) = v1;
        if (g < 31) {
            const float4* src = reinterpret_cast<const float4*>(
                E + (size_t)((g + 1) * 128 + scol) * EMB + skh);
            v0 = src[0]; v1 = src[1];
        }
        __syncthreads();
        #pragma unroll
        for (int cc = 0; cc < 4; ++cc) {
            const int c = j + 32 * cc;
            float4 e0 = *reinterpret_cast<const float4*>(&cl[c][0]);
            float4 e1 = *reinterpret_cast<const float4*>(&cl[c][4]);
            float4 e2 = *reinterpret_cast<const float4*>(&cl[c][8]);
            float4 e3 = *reinterpret_cast<const float4*>(&cl[c][12]);
            #pragma unroll
            for (int rr = 0; rr < 2; ++rr) {
                float s = er[rr][0]*e0.x + er[rr][1]*e0.y + er[rr][2]*e0.z  + er[rr][3]*e0.w
                        + er[rr][4]*e1.x + er[rr][5]*e1.y + er[rr][6]*e1.z  + er[rr][7]*e1.w
                        + er[rr][8]*e2.x + er[rr][9]*e2.y + er[rr][10]*e2.z + er[rr][11]*e2.w
                        + er[rr][12]*e3.x+ er[rr][13]*e3.y+ er[rr][14]*e3.z + er[rr][15]*e3.w;
                float e = __expf(fmaxf(s, 0.0f));
                rsum[rr] += e;
                A[(size_t)(r0 + i + rr * 8) * NN + g * 128 + c] = f2bf(e);
            }
        }
    }
    #pragma unroll
    for (int off = 16; off > 0; off >>= 1) {
        rsum[0] += __shfl_xor(rsum[0], off, 64);
        rsum[1] += __shfl_xor(rsum[1], off, 64);
    }
    if (j == 0) {
        invsum[r0 + i]     = 1.0f / rsum[0];
        invsum[r0 + i + 8] = 1.0f / rsum[1];
    }
}

// ---------------------------------------------------------------------------
// Kernel 2: XT[b][c][m] (bf16) = X[b][m][c] (f32) — transpose + convert.
// ---------------------------------------------------------------------------
__global__ __launch_bounds__(256) void transpose_conv_kernel(
    const float* __restrict__ X, ushort* __restrict__ XT)
{
    const int m0 = blockIdx.x * 64;
    const int b  = blockIdx.y;
    const int t  = threadIdx.x;
    __shared__ float tile[64][68];
    const float* Xb = X + (size_t)b * NN * CIN;

    #pragma unroll
    for (int it = 0; it < 4; ++it) {
        int r  = (t >> 4) + it * 16;
        int c4 = (t & 15) * 4;
        float4 v = *reinterpret_cast<const float4*>(Xb + (size_t)(m0 + r) * CIN + c4);
        *reinterpret_cast<float4*>(&tile[r][c4]) = v;
    }
    __syncthreads();
    #pragma unroll
    for (int it = 0; it < 2; ++it) {
        int c  = (t >> 3) + it * 32;
        int k8 = (t & 7) * 8;
        ushort4 p0, p1;
        p0.x = f2bf(tile[k8+0][c]); p0.y = f2bf(tile[k8+1][c]);
        p0.z = f2bf(tile[k8+2][c]); p0.w = f2bf(tile[k8+3][c]);
        p1.x = f2bf(tile[k8+4][c]); p1.y = f2bf(tile[k8+5][c]);
        p1.z = f2bf(tile[k8+6][c]); p1.w = f2bf(tile[k8+7][c]);
        ushort* dst = XT + ((size_t)b * CIN + c) * NN + m0 + k8;
        *reinterpret_cast<ushort4*>(dst)     = p0;
        *reinterpret_cast<ushort4*>(dst + 4) = p1;
    }
}

// ---------------------------------------------------------------------------
// Kernel 3: wpT[d][o][ki] (bf16) = wp[d][ki][o] (f32).  grid 64 x 256.
// ---------------------------------------------------------------------------
__global__ __launch_bounds__(256) void wp_pack_kernel(
    const float* __restrict__ wp, ushort* __restrict__ wpT)
{
    const int d  = blockIdx.x >> 2;
    const int q  = blockIdx.x & 3;
    const int o  = q * 16 + (threadIdx.x >> 4);
    const int k0 = (threadIdx.x & 15) * 12;
    const float* src = wp + (size_t)d * 12288 + o;
    ushort* dst = wpT + ((size_t)d * 64 + o) * 192 + k0;
    #pragma unroll
    for (int j = 0; j < 12; ++j) dst[j] = f2bf(src[(size_t)(k0 + j) * 64]);
}

// ---------------------------------------------------------------------------
// Kernel 4/5: merged MFMA GEMM (m97 structure) — round-8 proven version.
// ---------------------------------------------------------------------------
__global__ __launch_bounds__(256) void gemm_merged_kernel(
    const ushort* __restrict__ A, const ushort* __restrict__ BT,
    ushort* __restrict__ part)
{
    __shared__ ushort Alds[128 * 64];
    __shared__ ushort Blds[128 * 64];

    const int bid = blockIdx.x;
    const int n   = bid & 7;
    const int m   = (bid >> 3) & 31;
    const int s   = bid >> 8;
    const int m0  = m * 128;
    const int c0  = n * 128;
    const int k0  = s * 1024;

    const int t = threadIdx.x;
    const int w = t >> 6;
    const int l = t & 63;

    const ushort* Ag = A  + (size_t)m0 * NN;
    const ushort* Bg = BT + (size_t)c0 * NN;

    const int srow = l >> 3;            // 0..7
    const int sch  = l & 7;             // 0..7

    f32x4 acc[4][4];
    #pragma unroll
    for (int mi = 0; mi < 4; ++mi)
        #pragma unroll
        for (int ni = 0; ni < 4; ++ni)
            acc[mi][ni] = (f32x4){0.f, 0.f, 0.f, 0.f};

    const int rl  = l & 15;
    const int hi  = l >> 4;
    const int wr  = w >> 1;             // 0..1
    const int wc  = w & 1;              // 0..1
    const int rsw = rl & 7;             // read-side swizzle key

    for (int kt = 0; kt < 16; ++kt) {
        const int ko = k0 + kt * 64;
        #pragma unroll
        for (int i = 0; i < 4; ++i) {
            const int ii = (w << 2) + i;       // 0..15 (wave-uniform)
            const int r  = (ii << 3) + srow;   // 0..127
            const int ch = sch ^ (r & 7);
            gload_lds16(Ag + (size_t)r * NN + ko + (ch << 3), &Alds[ii << 9]);
            gload_lds16(Bg + (size_t)r * NN + ko + (ch << 3), &Blds[ii << 9]);
        }
        __syncthreads();

        #pragma unroll
        for (int ks = 0; ks < 2; ++ks) {
            const int cb = (ks << 2) + hi;
            const int cx = (cb ^ rsw) << 3;
            short8v af[4], bf[4];
            #pragma unroll
            for (int mi = 0; mi < 4; ++mi) {
                const int R = wr * 64 + mi * 16 + rl;
                af[mi] = *reinterpret_cast<const short8v*>(&Alds[(R << 6) + cx]);
            }
            #pragma unroll
            for (int ni = 0; ni < 4; ++ni) {
                const int R = wc * 64 + ni * 16 + rl;
                bf[ni] = *reinterpret_cast<const short8v*>(&Blds[(R << 6) + cx]);
            }
            #pragma unroll
            for (int mi = 0; mi < 4; ++mi)
                #pragma unroll
                for (int ni = 0; ni < 4; ++ni)
                    acc[mi][ni] = __builtin_amdgcn_mfma_f32_16x16x32_bf16(
                        af[mi], bf[ni], acc[mi][ni], 0, 0, 0);
        }
        __syncthreads();
    }

    ushort* ps = part + (size_t)s * 1024 * NN;
    #pragma unroll
    for (int mi = 0; mi < 4; ++mi) {
        const int mrow = m0 + wr * 64 + mi * 16 + hi * 4;
        #pragma unroll
        for (int ni = 0; ni < 4; ++ni) {
            const int cp = c0 + wc * 64 + ni * 16 + rl;
            ushort4 pk;
            pk.x = f2bf(acc[mi][ni][0]); pk.y = f2bf(acc[mi][ni][1]);
            pk.z = f2bf(acc[mi][ni][2]); pk.w = f2bf(acc[mi][ni][3]);
            *reinterpret_cast<ushort4*>(ps + (size_t)cp * NN + mrow) = pk;
        }
    }
}

// ---------------------------------------------------------------------------
// Kernel 6: combine split-K partials + normalize + dual-layout write.
// val = alpha*invsum[m]*(p0+p1+p2+p3) - (dosub ? XT : 0)   at [c'][m]
// Yt (optional): transposed [c'][m] (gemm2 B-operand); Yn: normal [b][m][c]
// for apply's coalesced A-staging.  Block = one b x one 64-m tile.
// ---------------------------------------------------------------------------
__global__ __launch_bounds__(256) void combine_kernel(
    const ushort* __restrict__ part, const ushort* __restrict__ XT,
    const float* __restrict__ invsum, ushort* __restrict__ Yt,
    ushort* __restrict__ Yn, float alpha, int dosub)
{
    __shared__ ushort tile[64][72];

    const int bid = blockIdx.x;
    const int b   = bid >> 6;
    const int m0  = (bid & 63) * 64;
    const int t   = threadIdx.x;
    const int c   = t >> 2;           // 0..63
    const int ms  = (t & 3) * 16;     // 0,16,32,48
    const size_t S = (size_t)1024 * NN;
    const size_t base = ((size_t)(b * 64 + c)) * NN + m0 + ms;

    float r[16];
    {
        short8v p0 = *reinterpret_cast<const short8v*>(part + base);
        short8v p1 = *reinterpret_cast<const short8v*>(part + base + 8);
        #pragma unroll
        for (int j = 0; j < 8; ++j) { r[j] = bf2f((ushort)p0[j]); r[8 + j] = bf2f((ushort)p1[j]); }
    }
    #pragma unroll
    for (int s = 1; s < 4; ++s) {
        short8v p0 = *reinterpret_cast<const short8v*>(part + s * S + base);
        short8v p1 = *reinterpret_cast<const short8v*>(part + s * S + base + 8);
        #pragma unroll
        for (int j = 0; j < 8; ++j) { r[j] += bf2f((ushort)p0[j]); r[8 + j] += bf2f((ushort)p1[j]); }
    }
    {
        float4 iv0 = *reinterpret_cast<const float4*>(invsum + m0 + ms);
        float4 iv1 = *reinterpret_cast<const float4*>(invsum + m0 + ms + 4);
        float4 iv2 = *reinterpret_cast<const float4*>(invsum + m0 + ms + 8);
        float4 iv3 = *reinterpret_cast<const float4*>(invsum + m0 + ms + 12);
        float iv[16] = { iv0.x, iv0.y, iv0.z, iv0.w, iv1.x, iv1.y, iv1.z, iv1.w,
                         iv2.x, iv2.y, iv2.z, iv2.w, iv3.x, iv3.y, iv3.z, iv3.w };
        #pragma unroll
        for (int j = 0; j < 16; ++j) r[j] *= alpha * iv[j];
    }
    if (dosub) {
        short8v x0 = *reinterpret_cast<const short8v*>(XT + base);
        short8v x1 = *reinterpret_cast<const short8v*>(XT + base + 8);
        #pragma unroll
        for (int j = 0; j < 8; ++j) { r[j] -= bf2f((ushort)x0[j]); r[8 + j] -= bf2f((ushort)x1[j]); }
    }
    short8v o0, o1;
    #pragma unroll
    for (int j = 0; j < 8; ++j) { o0[j] = (short)f2bf(r[j]); o1[j] = (short)f2bf(r[8 + j]); }
    if (Yt) {
        *reinterpret_cast<short8v*>(Yt + base)     = o0;
        *reinterpret_cast<short8v*>(Yt + base + 8) = o1;
    }
    *reinterpret_cast<short8v*>(&tile[c][ms])     = o0;
    *reinterpret_cast<short8v*>(&tile[c][ms + 8]) = o1;
    __syncthreads();

    // transposed write: Yn[b][m0+mm][cs..cs+15]
    const int mm = t >> 2;
    const int cs = (t & 3) * 16;
    short8v v0, v1;
    #pragma unroll
    for (int j = 0; j < 8; ++j) {
        v0[j] = (short)tile[cs + j][mm];
        v1[j] = (short)tile[cs + 8 + j][mm];
    }
    ushort* dst = Yn + ((size_t)b * NN + m0 + mm) * CIN + cs;
    *reinterpret_cast<short8v*>(dst)     = v0;
    *reinterpret_cast<short8v*>(dst + 8) = v1;
}

// ---------------------------------------------------------------------------
// Kernel 7: apply v6.  out[b,n,o] = sum_d E[n,d]*( XG[b,n,:]@wpT[d] + bp[d,o] )
// = r8/r13 apply with the A-staging SCATTER replaced by coalesced b128
// row-major staging from normal-layout sources (X f32->bf16, Y1n, Y2n):
// 6 ds_write_b128/thread instead of 48 ds_write_b16 (the 7.6M-conflict cost).
// Frag reads, d-loop, epilogue unchanged.
// ---------------------------------------------------------------------------
__global__ __launch_bounds__(256) void apply_kernel(
    const float* __restrict__ X, const ushort* __restrict__ Y1n,
    const ushort* __restrict__ Y2n, const ushort* __restrict__ wpT,
    const float* __restrict__ E, const float* __restrict__ bp,
    float* __restrict__ out)
{
    __shared__ ushort Alds[64][200];
    __shared__ ushort Wlds[64][200];
    __shared__ float  Elds[64][17];
    __shared__ float  bplds[16 * 64];

    const int r0 = blockIdx.x * 64;
    const int b  = r0 >> 12;
    const int n0 = r0 & (NN - 1);
    const int t  = threadIdx.x;
    const int w  = t >> 6;
    const int l  = t & 63;

    {
        float4 ev = *reinterpret_cast<const float4*>(E + (size_t)n0 * EMB + t * 4);
        int rr = t >> 2, dd = (t & 3) * 4;
        Elds[rr][dd + 0] = ev.x; Elds[rr][dd + 1] = ev.y;
        Elds[rr][dd + 2] = ev.z; Elds[rr][dd + 3] = ev.w;
        float4 bv = *reinterpret_cast<const float4*>(bp + t * 4);
        *reinterpret_cast<float4*>(&bplds[t * 4]) = bv;
    }
    // A-staging: coalesced, row-major.  k = [X 0..63 | Y1n 64..127 | Y2n 128..191]
    {
        #pragma unroll
        for (int it = 0; it < 2; ++it) {
            const int row = (t >> 3) + it * 32;          // 0..63
            const int c8  = (t & 7) * 8;                 // 0..56
            const size_t rb = ((size_t)b * NN + n0 + row) * CIN + c8;
            float4 x0 = *reinterpret_cast<const float4*>(X + rb);
            float4 x1 = *reinterpret_cast<const float4*>(X + rb + 4);
            short8v v;
            v[0] = (short)f2bf(x0.x); v[1] = (short)f2bf(x0.y);
            v[2] = (short)f2bf(x0.z); v[3] = (short)f2bf(x0.w);
            v[4] = (short)f2bf(x1.x); v[5] = (short)f2bf(x1.y);
            v[6] = (short)f2bf(x1.z); v[7] = (short)f2bf(x1.w);
            *reinterpret_cast<short8v*>(&Alds[row][c8]) = v;
            *reinterpret_cast<short8v*>(&Alds[row][64 + c8]) =
                *reinterpret_cast<const short8v*>(Y1n + rb);
            *reinterpret_cast<short8v*>(&Alds[row][128 + c8]) =
                *reinterpret_cast<const short8v*>(Y2n + rb);
        }
    }
    __syncthreads();

    const int rl = l & 15;
    const int kq = (l >> 4) * 8;

    short8v af[6];
    #pragma unroll
    for (int ks = 0; ks < 6; ++ks)
        af[ks] = *reinterpret_cast<const short8v*>(&Alds[w * 16 + rl][ks * 32 + kq]);

    f32x4 mainacc[4];
    #pragma unroll
    for (int ni = 0; ni < 4; ++ni) mainacc[ni] = (f32x4){0.f, 0.f, 0.f, 0.f};

    const int wo = t >> 2;
    const int wk = (t & 3) * 48;

    for (int d = 0; d < EMB; ++d) {
        __syncthreads();
        {
            const ushort* src = wpT + ((size_t)(d * 64 + wo)) * 192 + wk;
            #pragma unroll
            for (int j = 0; j < 6; ++j) {
                short8v v = *reinterpret_cast<const short8v*>(src + j * 8);
                *reinterpret_cast<short8v*>(&Wlds[wo][wk + j * 8]) = v;
            }
        }
        __syncthreads();

        f32x4 tmp[4];
        #pragma unroll
        for (int ni = 0; ni < 4; ++ni) tmp[ni] = (f32x4){0.f, 0.f, 0.f, 0.f};
        #pragma unroll
        for (int ks = 0; ks < 6; ++ks) {
            #pragma unroll
            for (int ni = 0; ni < 4; ++ni) {
                short8v bfr = *reinterpret_cast<const short8v*>(
                    &Wlds[ni * 16 + rl][ks * 32 + kq]);
                tmp[ni] = __builtin_amdgcn_mfma_f32_16x16x32_bf16(
                    af[ks], bfr, tmp[ni], 0, 0, 0);
            }
        }
        float e[4];
        #pragma unroll
        for (int j = 0; j < 4; ++j) e[j] = Elds[w * 16 + (l >> 4) * 4 + j][d];
        #pragma unroll
        for (int ni = 0; ni < 4; ++ni)
            #pragma unroll
            for (int j = 0; j < 4; ++j)
                mainacc[ni][j] += e[j] * tmp[ni][j];
    }

    const int lr4 = (l >> 4) * 4;
    #pragma unroll
    for (int ni = 0; ni < 4; ++ni) {
        int col = ni * 16 + rl;
        #pragma unroll
        for (int j = 0; j < 4; ++j) {
            int locrow = w * 16 + lr4 + j;
            float bias = 0.0f;
            #pragma unroll
            for (int d = 0; d < EMB; ++d)
                bias += Elds[locrow][d] * bplds[d * 64 + col];
            out[((size_t)b * NN + n0 + locrow) * COUT + col] = mainacc[ni][j] + bias;
        }
    }
}

// ---------------------------------------------------------------------------
extern "C" void kernel_launch(void* const* d_in, const int* in_sizes, int n_in,
                              void* d_out, int out_size, void* d_ws, size_t ws_size,
                              hipStream_t stream)
{
    const float* X  = (const float*)d_in[0];  // [16,4096,64]
    const float* E  = (const float*)d_in[1];  // [4096,16]
    const float* wp = (const float*)d_in[2];  // [16,3,64,64]
    const float* bp = (const float*)d_in[3];  // [16,64]
    float* out = (float*)d_out;

    char* ws = (char*)d_ws;
    size_t off = 0;
    ushort* Abf  = (ushort*)(ws + off); off += (size_t)NN * NN * 2;        // 32 MB
    ushort* XT   = (ushort*)(ws + off); off += (size_t)BB * CIN * NN * 2;  //  8 MB
    ushort* Y1T  = (ushort*)(ws + off); off += (size_t)BB * CIN * NN * 2;  //  8 MB (reused as Y2n)
    ushort* Y1n  = (ushort*)(ws + off); off += (size_t)BB * CIN * NN * 2;  //  8 MB
    ushort* wpT  = (ushort*)(ws + off); off += (size_t)EMB * 64 * 192 * 2; // 384 KB
    float*  invs = (float*)(ws + off);  off += (size_t)NN * 4;             // 16 KB
    off = (off + 255) & ~(size_t)255;
    ushort* part = (ushort*)(ws + off);  // 4 x 1024 x 4096 bf16 = 33.5 MB
    ushort* Y2n  = Y1T;                  // Y1T dead after gemm2 reads it

    adj_softmax_kernel    <<<NN / 16, 256, 0, stream>>>(E, Abf, invs);
    transpose_conv_kernel <<<dim3(NN / 64, BB), 256, 0, stream>>>(X, XT);
    wp_pack_kernel        <<<64, 256, 0, stream>>>(wp, wpT);
    gemm_merged_kernel    <<<1024, 256, 0, stream>>>(Abf, XT, part);
    combine_kernel        <<<1024, 256, 0, stream>>>(part, XT, invs, Y1T, Y1n, 1.0f, 0);
    gemm_merged_kernel    <<<1024, 256, 0, stream>>>(Abf, Y1T, part);
    combine_kernel        <<<1024, 256, 0, stream>>>(part, XT, invs, nullptr, Y2n, 2.0f, 1);
    apply_kernel          <<<1024, 256, 0, stream>>>(X, Y1n, Y2n, wpT, E, bp, out);
}

// Round 15
// 204.532 us; speedup vs baseline: 1.0761x; 1.0761x over previous
//
#include <hip/hip_runtime.h>
#include <cstdint>

#define NN   4096
#define EMB  16
#define CIN  64
#define COUT 64
#define BB   16

typedef __attribute__((ext_vector_type(8))) short short8v;
typedef __attribute__((ext_vector_type(4))) float f32x4;

__device__ inline ushort f2bf(float f) {
    uint32_t u = __builtin_bit_cast(uint32_t, f);
    uint32_t r = (u + 0x7FFFu + ((u >> 16) & 1u)) >> 16;
    return (ushort)r;
}
__device__ inline float bf2f(ushort u) {
    uint32_t v = ((uint32_t)u) << 16;
    return __builtin_bit_cast(float, v);
}
// async global->LDS, 16B per lane. LDS dest = wave-uniform base + lane*16.
__device__ inline void gload_lds16(const ushort* g, ushort* l) {
    __builtin_amdgcn_global_load_lds(
        (const __attribute__((address_space(1))) void*)g,
        (__attribute__((address_space(3))) void*)l, 16, 0, 0);
}

// ---------------------------------------------------------------------------
// Kernel 1: A = exp(relu(E @ E^T)) UNNORMALIZED bf16 + invsum[n] = 1/rowsum.
// (r13-proven; normalization folded into combine)
// ---------------------------------------------------------------------------
__global__ __launch_bounds__(256) void adj_softmax_kernel(
    const float* __restrict__ E, ushort* __restrict__ A,
    float* __restrict__ invsum)
{
    __shared__ float cl[128][20];

    const int r0 = blockIdx.x * 16;
    const int t  = threadIdx.x;
    const int i  = t >> 5;        // 0..7
    const int j  = t & 31;        // 0..31

    float er[2][16];
    #pragma unroll
    for (int rr = 0; rr < 2; ++rr) {
        const float4* ep = reinterpret_cast<const float4*>(
            E + (size_t)(r0 + i + rr * 8) * EMB);
        float4 a = ep[0], b = ep[1], c = ep[2], d = ep[3];
        er[rr][0]=a.x; er[rr][1]=a.y; er[rr][2]=a.z; er[rr][3]=a.w;
        er[rr][4]=b.x; er[rr][5]=b.y; er[rr][6]=b.z; er[rr][7]=b.w;
        er[rr][8]=c.x; er[rr][9]=c.y; er[rr][10]=c.z; er[rr][11]=c.w;
        er[rr][12]=d.x; er[rr][13]=d.y; er[rr][14]=d.z; er[rr][15]=d.w;
    }

    const int scol = t >> 1;
    const int skh  = (t & 1) * 8;

    float rsum[2] = {0.0f, 0.0f};

    float4 v0, v1;
    {
        const float4* src = reinterpret_cast<const float4*>(
            E + (size_t)scol * EMB + skh);
        v0 = src[0]; v1 = src[1];
    }
    for (int g = 0; g < 32; ++g) {
        __syncthreads();
        *reinterpret_cast<float4*>(&cl[scol][skh])     = v0;
        *reinterpret_cast<float4*>(&cl[scol][skh + 4]) = v1;
        if (g < 31) {
            const float4* src = reinterpret_cast<const float4*>(
                E + (size_t)((g + 1) * 128 + scol) * EMB + skh);
            v0 = src[0]; v1 = src[1];
        }
        __syncthreads();
        #pragma unroll
        for (int cc = 0; cc < 4; ++cc) {
            const int c = j + 32 * cc;
            float4 e0 = *reinterpret_cast<const float4*>(&cl[c][0]);
            float4 e1 = *reinterpret_cast<const float4*>(&cl[c][4]);
            float4 e2 = *reinterpret_cast<const float4*>(&cl[c][8]);
            float4 e3 = *reinterpret_cast<const float4*>(&cl[c][12]);
            #pragma unroll
            for (int rr = 0; rr < 2; ++rr) {
                float s = er[rr][0]*e0.x + er[rr][1]*e0.y + er[rr][2]*e0.z  + er[rr][3]*e0.w
                        + er[rr][4]*e1.x + er[rr][5]*e1.y + er[rr][6]*e1.z  + er[rr][7]*e1.w
                        + er[rr][8]*e2.x + er[rr][9]*e2.y + er[rr][10]*e2.z + er[rr][11]*e2.w
                        + er[rr][12]*e3.x+ er[rr][13]*e3.y+ er[rr][14]*e3.z + er[rr][15]*e3.w;
                float e = __expf(fmaxf(s, 0.0f));
                rsum[rr] += e;
                A[(size_t)(r0 + i + rr * 8) * NN + g * 128 + c] = f2bf(e);
            }
        }
    }
    #pragma unroll
    for (int off = 16; off > 0; off >>= 1) {
        rsum[0] += __shfl_xor(rsum[0], off, 64);
        rsum[1] += __shfl_xor(rsum[1], off, 64);
    }
    if (j == 0) {
        invsum[r0 + i]     = 1.0f / rsum[0];
        invsum[r0 + i + 8] = 1.0f / rsum[1];
    }
}

// ---------------------------------------------------------------------------
// Kernel 2: XT[b][c][m] (bf16) = X[b][m][c] (f32) — transpose + convert.
// ---------------------------------------------------------------------------
__global__ __launch_bounds__(256) void transpose_conv_kernel(
    const float* __restrict__ X, ushort* __restrict__ XT)
{
    const int m0 = blockIdx.x * 64;
    const int b  = blockIdx.y;
    const int t  = threadIdx.x;
    __shared__ float tile[64][68];
    const float* Xb = X + (size_t)b * NN * CIN;

    #pragma unroll
    for (int it = 0; it < 4; ++it) {
        int r  = (t >> 4) + it * 16;
        int c4 = (t & 15) * 4;
        float4 v = *reinterpret_cast<const float4*>(Xb + (size_t)(m0 + r) * CIN + c4);
        *reinterpret_cast<float4*>(&tile[r][c4]) = v;
    }
    __syncthreads();
    #pragma unroll
    for (int it = 0; it < 2; ++it) {
        int c  = (t >> 3) + it * 32;
        int k8 = (t & 7) * 8;
        ushort4 p0, p1;
        p0.x = f2bf(tile[k8+0][c]); p0.y = f2bf(tile[k8+1][c]);
        p0.z = f2bf(tile[k8+2][c]); p0.w = f2bf(tile[k8+3][c]);
        p1.x = f2bf(tile[k8+4][c]); p1.y = f2bf(tile[k8+5][c]);
        p1.z = f2bf(tile[k8+6][c]); p1.w = f2bf(tile[k8+7][c]);
        ushort* dst = XT + ((size_t)b * CIN + c) * NN + m0 + k8;
        *reinterpret_cast<ushort4*>(dst)     = p0;
        *reinterpret_cast<ushort4*>(dst + 4) = p1;
    }
}

// ---------------------------------------------------------------------------
// Kernel 3: wpT[d][o][ki] (bf16) = wp[d][ki][o] (f32).  grid 64 x 256.
// ---------------------------------------------------------------------------
__global__ __launch_bounds__(256) void wp_pack_kernel(
    const float* __restrict__ wp, ushort* __restrict__ wpT)
{
    const int d  = blockIdx.x >> 2;
    const int q  = blockIdx.x & 3;
    const int o  = q * 16 + (threadIdx.x >> 4);
    const int k0 = (threadIdx.x & 15) * 12;
    const float* src = wp + (size_t)d * 12288 + o;
    ushort* dst = wpT + ((size_t)d * 64 + o) * 192 + k0;
    #pragma unroll
    for (int j = 0; j < 12; ++j) dst[j] = f2bf(src[(size_t)(k0 + j) * 64]);
}

// ---------------------------------------------------------------------------
// Kernel 4/5: merged MFMA GEMM (m97 structure).
// v2 XCD partition: XCD pinned to an M-GROUP (4 m-tiles = 4 MB A-panel,
// L2-fit) instead of an n-panel (which streamed all 32 MB of A through
// each XCD's L2: unique working set 33 MB -> 12 MB per XCD).
// bid = mg + 8*(mi + 4*(n + 8*s)); all co-resident blocks on XCD mg share
// A rows [mg*512, mg*512+512).
// ---------------------------------------------------------------------------
__global__ __launch_bounds__(256) void gemm_merged_kernel(
    const ushort* __restrict__ A, const ushort* __restrict__ BT,
    ushort* __restrict__ part)
{
    __shared__ ushort Alds[128 * 64];
    __shared__ ushort Blds[128 * 64];

    const int bid = blockIdx.x;
    const int mg  = bid & 7;            // XCD id = m-group
    const int rr_ = bid >> 3;           // 0..127
    const int mi_ = rr_ & 3;
    const int n   = (rr_ >> 2) & 7;
    const int s   = rr_ >> 5;           // 0..3
    const int m   = mg * 4 + mi_;       // 0..31
    const int m0  = m * 128;
    const int c0  = n * 128;
    const int k0  = s * 1024;

    const int t = threadIdx.x;
    const int w = t >> 6;
    const int l = t & 63;

    const ushort* Ag = A  + (size_t)m0 * NN;
    const ushort* Bg = BT + (size_t)c0 * NN;

    const int srow = l >> 3;            // 0..7
    const int sch  = l & 7;             // 0..7

    f32x4 acc[4][4];
    #pragma unroll
    for (int mi = 0; mi < 4; ++mi)
        #pragma unroll
        for (int ni = 0; ni < 4; ++ni)
            acc[mi][ni] = (f32x4){0.f, 0.f, 0.f, 0.f};

    const int rl  = l & 15;
    const int hi  = l >> 4;
    const int wr  = w >> 1;             // 0..1
    const int wc  = w & 1;              // 0..1
    const int rsw = rl & 7;             // read-side swizzle key

    for (int kt = 0; kt < 16; ++kt) {
        const int ko = k0 + kt * 64;
        #pragma unroll
        for (int i = 0; i < 4; ++i) {
            const int ii = (w << 2) + i;       // 0..15 (wave-uniform)
            const int r  = (ii << 3) + srow;   // 0..127
            const int ch = sch ^ (r & 7);
            gload_lds16(Ag + (size_t)r * NN + ko + (ch << 3), &Alds[ii << 9]);
            gload_lds16(Bg + (size_t)r * NN + ko + (ch << 3), &Blds[ii << 9]);
        }
        __syncthreads();

        #pragma unroll
        for (int ks = 0; ks < 2; ++ks) {
            const int cb = (ks << 2) + hi;
            const int cx = (cb ^ rsw) << 3;
            short8v af[4], bf[4];
            #pragma unroll
            for (int mi = 0; mi < 4; ++mi) {
                const int R = wr * 64 + mi * 16 + rl;
                af[mi] = *reinterpret_cast<const short8v*>(&Alds[(R << 6) + cx]);
            }
            #pragma unroll
            for (int ni = 0; ni < 4; ++ni) {
                const int R = wc * 64 + ni * 16 + rl;
                bf[ni] = *reinterpret_cast<const short8v*>(&Blds[(R << 6) + cx]);
            }
            #pragma unroll
            for (int mi = 0; mi < 4; ++mi)
                #pragma unroll
                for (int ni = 0; ni < 4; ++ni)
                    acc[mi][ni] = __builtin_amdgcn_mfma_f32_16x16x32_bf16(
                        af[mi], bf[ni], acc[mi][ni], 0, 0, 0);
        }
        __syncthreads();
    }

    ushort* ps = part + (size_t)s * 1024 * NN;
    #pragma unroll
    for (int mi = 0; mi < 4; ++mi) {
        const int mrow = m0 + wr * 64 + mi * 16 + hi * 4;
        #pragma unroll
        for (int ni = 0; ni < 4; ++ni) {
            const int cp = c0 + wc * 64 + ni * 16 + rl;
            ushort4 pk;
            pk.x = f2bf(acc[mi][ni][0]); pk.y = f2bf(acc[mi][ni][1]);
            pk.z = f2bf(acc[mi][ni][2]); pk.w = f2bf(acc[mi][ni][3]);
            *reinterpret_cast<ushort4*>(ps + (size_t)cp * NN + mrow) = pk;
        }
    }
}

// ---------------------------------------------------------------------------
// Kernel 6: combine 4 bf16 split-K partials + normalize + epilogue.
// Yt[c'][m] = f2bf( alpha*invsum[m]*(p0+p1+p2+p3) - (dosub ? XT : 0) )
// ---------------------------------------------------------------------------
__global__ __launch_bounds__(256) void combine_kernel(
    const ushort* __restrict__ part, const ushort* __restrict__ XT,
    const float* __restrict__ invsum, ushort* __restrict__ Yt,
    float alpha, int dosub)
{
    const size_t idx = ((size_t)blockIdx.x * 256 + threadIdx.x) * 8;
    const size_t S = (size_t)1024 * NN;
    const int m8 = (int)(idx & (NN - 1));
    short8v p0 = *reinterpret_cast<const short8v*>(part + idx);
    short8v p1 = *reinterpret_cast<const short8v*>(part + S + idx);
    short8v p2 = *reinterpret_cast<const short8v*>(part + 2 * S + idx);
    short8v p3 = *reinterpret_cast<const short8v*>(part + 3 * S + idx);
    float4 iv0 = *reinterpret_cast<const float4*>(invsum + m8);
    float4 iv1 = *reinterpret_cast<const float4*>(invsum + m8 + 4);
    float iv[8] = { iv0.x, iv0.y, iv0.z, iv0.w, iv1.x, iv1.y, iv1.z, iv1.w };
    float r[8];
    #pragma unroll
    for (int j = 0; j < 8; ++j)
        r[j] = alpha * iv[j] * (bf2f((ushort)p0[j]) + bf2f((ushort)p1[j])
                              + bf2f((ushort)p2[j]) + bf2f((ushort)p3[j]));
    if (dosub) {
        short8v xv = *reinterpret_cast<const short8v*>(XT + idx);
        #pragma unroll
        for (int j = 0; j < 8; ++j) r[j] -= bf2f((ushort)xv[j]);
    }
    short8v o;
    #pragma unroll
    for (int j = 0; j < 8; ++j) o[j] = (short)f2bf(r[j]);
    *reinterpret_cast<short8v*>(Yt + idx) = o;
}

// ---------------------------------------------------------------------------
// Kernel 7: apply (round-8/13 proven version).
// out[b,n,o] = sum_d E[n,d]*( XG[b,n,:]@wpT[d] + bp[d,o] )
// ---------------------------------------------------------------------------
__global__ __launch_bounds__(256) void apply_kernel(
    const ushort* __restrict__ XT, const ushort* __restrict__ Y1T,
    const ushort* __restrict__ Y2T, const ushort* __restrict__ wpT,
    const float* __restrict__ E, const float* __restrict__ bp,
    float* __restrict__ out)
{
    __shared__ ushort Alds[64][200];
    __shared__ ushort Wlds[64][200];
    __shared__ float  Elds[64][17];
    __shared__ float  bplds[16 * 64];

    const int r0 = blockIdx.x * 64;
    const int b  = r0 >> 12;
    const int n0 = r0 & (NN - 1);
    const int t  = threadIdx.x;
    const int w  = t >> 6;
    const int l  = t & 63;

    {
        float4 ev = *reinterpret_cast<const float4*>(E + (size_t)n0 * EMB + t * 4);
        int rr = t >> 2, dd = (t & 3) * 4;
        Elds[rr][dd + 0] = ev.x; Elds[rr][dd + 1] = ev.y;
        Elds[rr][dd + 2] = ev.z; Elds[rr][dd + 3] = ev.w;
        float4 bv = *reinterpret_cast<const float4*>(bp + t * 4);
        *reinterpret_cast<float4*>(&bplds[t * 4]) = bv;
    }
    {
        const int c  = t >> 2;
        const int mg = (t & 3) * 16;
        const size_t base = ((size_t)b * CIN + c) * NN + n0 + mg;
        const ushort* __restrict__ srcs[3] = {XT, Y1T, Y2T};
        #pragma unroll
        for (int ks = 0; ks < 3; ++ks) {
            short8v v0 = *reinterpret_cast<const short8v*>(srcs[ks] + base);
            short8v v1 = *reinterpret_cast<const short8v*>(srcs[ks] + base + 8);
            #pragma unroll
            for (int j = 0; j < 8; ++j) Alds[mg + j][ks * 64 + c] = (ushort)v0[j];
            #pragma unroll
            for (int j = 0; j < 8; ++j) Alds[mg + 8 + j][ks * 64 + c] = (ushort)v1[j];
        }
    }
    __syncthreads();

    const int rl = l & 15;
    const int kq = (l >> 4) * 8;

    short8v af[6];
    #pragma unroll
    for (int ks = 0; ks < 6; ++ks)
        af[ks] = *reinterpret_cast<const short8v*>(&Alds[w * 16 + rl][ks * 32 + kq]);

    f32x4 mainacc[4];
    #pragma unroll
    for (int ni = 0; ni < 4; ++ni) mainacc[ni] = (f32x4){0.f, 0.f, 0.f, 0.f};

    const int wo = t >> 2;
    const int wk = (t & 3) * 48;

    for (int d = 0; d < EMB; ++d) {
        __syncthreads();
        {
            const ushort* src = wpT + ((size_t)(d * 64 + wo)) * 192 + wk;
            #pragma unroll
            for (int j = 0; j < 6; ++j) {
                short8v v = *reinterpret_cast<const short8v*>(src + j * 8);
                *reinterpret_cast<short8v*>(&Wlds[wo][wk + j * 8]) = v;
            }
        }
        __syncthreads();

        f32x4 tmp[4];
        #pragma unroll
        for (int ni = 0; ni < 4; ++ni) tmp[ni] = (f32x4){0.f, 0.f, 0.f, 0.f};
        #pragma unroll
        for (int ks = 0; ks < 6; ++ks) {
            #pragma unroll
            for (int ni = 0; ni < 4; ++ni) {
                short8v bfr = *reinterpret_cast<const short8v*>(
                    &Wlds[ni * 16 + rl][ks * 32 + kq]);
                tmp[ni] = __builtin_amdgcn_mfma_f32_16x16x32_bf16(
                    af[ks], bfr, tmp[ni], 0, 0, 0);
            }
        }
        float e[4];
        #pragma unroll
        for (int j = 0; j < 4; ++j) e[j] = Elds[w * 16 + (l >> 4) * 4 + j][d];
        #pragma unroll
        for (int ni = 0; ni < 4; ++ni)
            #pragma unroll
            for (int j = 0; j < 4; ++j)
                mainacc[ni][j] += e[j] * tmp[ni][j];
    }

    const int lr4 = (l >> 4) * 4;
    #pragma unroll
    for (int ni = 0; ni < 4; ++ni) {
        int col = ni * 16 + rl;
        #pragma unroll
        for (int j = 0; j < 4; ++j) {
            int locrow = w * 16 + lr4 + j;
            float bias = 0.0f;
            #pragma unroll
            for (int d = 0; d < EMB; ++d)
                bias += Elds[locrow][d] * bplds[d * 64 + col];
            out[((size_t)b * NN + n0 + locrow) * COUT + col] = mainacc[ni][j] + bias;
        }
    }
}

// ---------------------------------------------------------------------------
extern "C" void kernel_launch(void* const* d_in, const int* in_sizes, int n_in,
                              void* d_out, int out_size, void* d_ws, size_t ws_size,
                              hipStream_t stream)
{
    const float* X  = (const float*)d_in[0];  // [16,4096,64]
    const float* E  = (const float*)d_in[1];  // [4096,16]
    const float* wp = (const float*)d_in[2];  // [16,3,64,64]
    const float* bp = (const float*)d_in[3];  // [16,64]
    float* out = (float*)d_out;

    char* ws = (char*)d_ws;
    size_t off = 0;
    ushort* Abf  = (ushort*)(ws + off); off += (size_t)NN * NN * 2;        // 32 MB
    ushort* XT   = (ushort*)(ws + off); off += (size_t)BB * CIN * NN * 2;  //  8 MB
    ushort* Y1T  = (ushort*)(ws + off); off += (size_t)BB * CIN * NN * 2;  //  8 MB
    ushort* Y2T  = (ushort*)(ws + off); off += (size_t)BB * CIN * NN * 2;  //  8 MB
    ushort* wpT  = (ushort*)(ws + off); off += (size_t)EMB * 64 * 192 * 2; // 384 KB
    float*  invs = (float*)(ws + off);  off += (size_t)NN * 4;             // 16 KB
    off = (off + 255) & ~(size_t)255;
    ushort* part = (ushort*)(ws + off);  // 4 x 1024 x 4096 bf16 = 33.5 MB

    const int NELEM_BLOCKS = (BB * CIN * NN) / (256 * 8);  // 2048

    adj_softmax_kernel    <<<NN / 16, 256, 0, stream>>>(E, Abf, invs);
    transpose_conv_kernel <<<dim3(NN / 64, BB), 256, 0, stream>>>(X, XT);
    wp_pack_kernel        <<<64, 256, 0, stream>>>(wp, wpT);
    gemm_merged_kernel    <<<1024, 256, 0, stream>>>(Abf, XT, part);
    combine_kernel        <<<NELEM_BLOCKS, 256, 0, stream>>>(part, XT, invs, Y1T, 1.0f, 0);
    gemm_merged_kernel    <<<1024, 256, 0, stream>>>(Abf, Y1T, part);
    combine_kernel        <<<NELEM_BLOCKS, 256, 0, stream>>>(part, XT, invs, Y2T, 2.0f, 1);
    apply_kernel          <<<1024, 256, 0, stream>>>(XT, Y1T, Y2T, wpT, E, bp, out);
}